// Round 1
// baseline (427.486 us; speedup 1.0000x reference)
//
#include <hip/hip_runtime.h>
#include <hip/hip_bf16.h>

// Problem constants
#define T_TOK 2048
#define HID   1024
#define FF    3584
#define NE    8
#define TOPK  2

typedef __bf16 bf16x8 __attribute__((ext_vector_type(8)));
typedef float  f32x4  __attribute__((ext_vector_type(4)));
typedef unsigned short u16x8 __attribute__((ext_vector_type(8)));

// ---- workspace layout (bytes) ----
#define WS_COUNTS   0u           // int[8]
#define WS_OFFSETS  64u          // int[8]
#define WS_TOPKI    128u         // int[4096]
#define WS_TOPKW    16512u       // float[4096]
#define WS_SLOTPOS  32896u       // int[4096]
#define WS_SLOTROW  49280u       // int[4096]
#define WS_ROUTETOK 65664u       // int[8*2048]
#define WS_XBF      131328u      // ushort[2048*1024]  (4 MB)
#define WS_ACT      (WS_XBF + 2048u*1024u*2u)          // ushort[4096*3584] (29.4 MB)
#define WS_Y        (WS_ACT + 4096u*3584u*2u)          // float[4096*1024]  (16 MB)
// total ~48.2 MB

static __device__ __forceinline__ unsigned short f2bf(float f) {
    unsigned int u = __builtin_bit_cast(unsigned int, f);
    u += 0x7FFFu + ((u >> 16) & 1u);   // round-to-nearest-even
    return (unsigned short)(u >> 16);
}

// ---------------- x -> bf16 ----------------
__global__ void k_cvt_x(const float* __restrict__ x, unsigned short* __restrict__ xb) {
    int i = blockIdx.x * blockDim.x + threadIdx.x;   // 524288 threads, 4 elems each
    float4 v = ((const float4*)x)[i];
    ushort4 o;
    o.x = f2bf(v.x); o.y = f2bf(v.y); o.z = f2bf(v.z); o.w = f2bf(v.w);
    ((ushort4*)xb)[i] = o;
}

// ---------------- router: logits -> top2 -> renorm; atomic slot alloc ----------------
__global__ void k_router(const float* __restrict__ x, const float* __restrict__ gw,
                         int* __restrict__ counts, int* __restrict__ topki,
                         float* __restrict__ topkw, int* __restrict__ slotpos) {
    int t = blockIdx.x;
    int l = threadIdx.x;           // 64 lanes (one wave)
    const float* xr = x + (size_t)t * HID;
    float acc[NE];
#pragma unroll
    for (int e = 0; e < NE; ++e) acc[e] = 0.f;
#pragma unroll
    for (int i = 0; i < HID / 64; ++i) {
        int h = l + 64 * i;
        float xv = xr[h];
#pragma unroll
        for (int e = 0; e < NE; ++e) acc[e] += xv * gw[e * HID + h];
    }
#pragma unroll
    for (int e = 0; e < NE; ++e) {
#pragma unroll
        for (int off = 32; off; off >>= 1) acc[e] += __shfl_xor(acc[e], off);
    }
    if (l == 0) {
        float best = -1e30f, second = -1e30f;
        int bi = 0, si = 0;
#pragma unroll
        for (int e = 0; e < NE; ++e) {
            float v = acc[e];
            if (v > best) { second = best; si = bi; best = v; bi = e; }
            else if (v > second) { second = v; si = e; }
        }
        float w0 = 1.f / (1.f + __expf(second - best));
        float w1 = 1.f - w0;
        topki[2 * t] = bi;  topki[2 * t + 1] = si;
        topkw[2 * t] = w0;  topkw[2 * t + 1] = w1;
        slotpos[2 * t]     = atomicAdd(&counts[bi], 1);
        slotpos[2 * t + 1] = atomicAdd(&counts[si], 1);
    }
}

// ---------------- exclusive prefix over 8 counts ----------------
__global__ void k_prefix(const int* __restrict__ counts, int* __restrict__ offsets) {
    if (threadIdx.x == 0) {
        int o = 0;
#pragma unroll
        for (int e = 0; e < NE; ++e) { offsets[e] = o; o += counts[e]; }
    }
}

// ---------------- fill routing arrays ----------------
__global__ void k_fill(const int* __restrict__ topki, const int* __restrict__ slotpos,
                       const int* __restrict__ offsets, int* __restrict__ routetok,
                       int* __restrict__ slotrow) {
    int j = blockIdx.x * blockDim.x + threadIdx.x;
    if (j >= T_TOK * TOPK) return;
    int e = topki[j];
    int row = offsets[e] + slotpos[j];
    routetok[row] = j >> 1;
    slotrow[j] = row;
}

// ---------------- GEMM1: act = silu(Xe@w1^T) * (Xe@w3^T)  (gathered rows) ----------------
__global__ __launch_bounds__(256) void k_gemm1(
    const unsigned short* __restrict__ xb, const float* __restrict__ w1,
    const float* __restrict__ w3, const int* __restrict__ counts,
    const int* __restrict__ offsets, const int* __restrict__ routetok,
    unsigned short* __restrict__ act)
{
    int e = blockIdx.z, mt = blockIdx.y, nt = blockIdx.x;
    int cnt = counts[e];
    int rbase = mt * 128;
    if (rbase >= cnt) return;
    int obase = offsets[e];
    int fbase = nt * 64;

    __shared__ __align__(16) unsigned short lA[128 * 72];
    __shared__ __align__(16) unsigned short lB1[64 * 72];
    __shared__ __align__(16) unsigned short lB3[64 * 72];
    __shared__ int ltok[128];

    int tid = threadIdx.x;
    if (tid < 128) {
        int r = rbase + tid;
        ltok[tid] = (r < cnt) ? routetok[obase + r] : 0;
    }
    __syncthreads();

    int lane = tid & 63, wv = tid >> 6, wr = wv >> 1, wc = wv & 1;
    f32x4 accg[4][2], accu[4][2];
#pragma unroll
    for (int m = 0; m < 4; ++m)
#pragma unroll
        for (int n = 0; n < 2; ++n) {
            accg[m][n] = (f32x4){0.f, 0.f, 0.f, 0.f};
            accu[m][n] = (f32x4){0.f, 0.f, 0.f, 0.f};
        }

    const float* w1e = w1 + ((size_t)e * FF + fbase) * HID;
    const float* w3e = w3 + ((size_t)e * FF + fbase) * HID;

    for (int kt = 0; kt < HID / 64; ++kt) {
        int hb = kt * 64;
        // stage A (gathered x rows, bf16 16B loads)
#pragma unroll
        for (int i = 0; i < 4; ++i) {
            int c = tid + 256 * i;
            int r = c >> 3, c8 = (c & 7) * 8;
            const unsigned short* src = xb + (size_t)ltok[r] * HID + hb + c8;
            *(u16x8*)(lA + r * 72 + c8) = *(const u16x8*)src;
        }
        // stage B1/B3 (f32 -> bf16 in flight)
#pragma unroll
        for (int i = 0; i < 4; ++i) {
            int c = tid + 256 * i;
            int fr = c >> 4, c4 = (c & 15) * 4;
            float4 v1 = *(const float4*)(w1e + (size_t)fr * HID + hb + c4);
            float4 v3 = *(const float4*)(w3e + (size_t)fr * HID + hb + c4);
            ushort4 b1v, b3v;
            b1v.x = f2bf(v1.x); b1v.y = f2bf(v1.y); b1v.z = f2bf(v1.z); b1v.w = f2bf(v1.w);
            b3v.x = f2bf(v3.x); b3v.y = f2bf(v3.y); b3v.z = f2bf(v3.z); b3v.w = f2bf(v3.w);
            *(ushort4*)(lB1 + fr * 72 + c4) = b1v;
            *(ushort4*)(lB3 + fr * 72 + c4) = b3v;
        }
        __syncthreads();
#pragma unroll
        for (int kk = 0; kk < 64; kk += 32) {
            int kcol = kk + (lane >> 4) * 8;
            bf16x8 a[4], b1[2], b3[2];
#pragma unroll
            for (int m = 0; m < 4; ++m)
                a[m] = *(const bf16x8*)(lA + (wr * 64 + m * 16 + (lane & 15)) * 72 + kcol);
#pragma unroll
            for (int n = 0; n < 2; ++n) {
                b1[n] = *(const bf16x8*)(lB1 + (wc * 32 + n * 16 + (lane & 15)) * 72 + kcol);
                b3[n] = *(const bf16x8*)(lB3 + (wc * 32 + n * 16 + (lane & 15)) * 72 + kcol);
            }
#pragma unroll
            for (int m = 0; m < 4; ++m)
#pragma unroll
                for (int n = 0; n < 2; ++n) {
                    accg[m][n] = __builtin_amdgcn_mfma_f32_16x16x32_bf16(a[m], b1[n], accg[m][n], 0, 0, 0);
                    accu[m][n] = __builtin_amdgcn_mfma_f32_16x16x32_bf16(a[m], b3[n], accu[m][n], 0, 0, 0);
                }
        }
        __syncthreads();
    }

    // epilogue: silu(g)*u -> bf16 act
#pragma unroll
    for (int m = 0; m < 4; ++m)
#pragma unroll
        for (int n = 0; n < 2; ++n)
#pragma unroll
            for (int r = 0; r < 4; ++r) {
                int lr = wr * 64 + m * 16 + (lane >> 4) * 4 + r;
                if (rbase + lr < cnt) {
                    float g = accg[m][n][r], u = accu[m][n][r];
                    float s = g / (1.f + __expf(-g));
                    int col = fbase + wc * 32 + n * 16 + (lane & 15);
                    act[(size_t)(obase + rbase + lr) * FF + col] = f2bf(s * u);
                }
            }
}

// ---------------- GEMM2: y = act @ w2^T  (rows already grouped) ----------------
__global__ __launch_bounds__(256) void k_gemm2(
    const unsigned short* __restrict__ act, const float* __restrict__ w2,
    const int* __restrict__ counts, const int* __restrict__ offsets,
    float* __restrict__ y)
{
    int e = blockIdx.z, mt = blockIdx.y, nt = blockIdx.x;
    int cnt = counts[e];
    int rbase = mt * 128;
    if (rbase >= cnt) return;
    int obase = offsets[e];
    int hbase = nt * 64;

    __shared__ __align__(16) unsigned short lA[128 * 72];
    __shared__ __align__(16) unsigned short lB[64 * 72];

    int tid = threadIdx.x;
    int lane = tid & 63, wv = tid >> 6, wr = wv >> 1, wc = wv & 1;
    f32x4 acc[4][2];
#pragma unroll
    for (int m = 0; m < 4; ++m)
#pragma unroll
        for (int n = 0; n < 2; ++n) acc[m][n] = (f32x4){0.f, 0.f, 0.f, 0.f};

    const float* w2e = w2 + ((size_t)e * HID + hbase) * FF;

    for (int kt = 0; kt < FF / 64; ++kt) {
        int fb = kt * 64;
#pragma unroll
        for (int i = 0; i < 4; ++i) {
            int c = tid + 256 * i;
            int r = c >> 3, c8 = (c & 7) * 8;
            int rowg = obase + rbase + r;
            if (rowg > 4095) rowg = 4095;
            const unsigned short* src = act + (size_t)rowg * FF + fb + c8;
            *(u16x8*)(lA + r * 72 + c8) = *(const u16x8*)src;
        }
#pragma unroll
        for (int i = 0; i < 4; ++i) {
            int c = tid + 256 * i;
            int hr = c >> 4, c4 = (c & 15) * 4;
            float4 v = *(const float4*)(w2e + (size_t)hr * FF + fb + c4);
            ushort4 bv;
            bv.x = f2bf(v.x); bv.y = f2bf(v.y); bv.z = f2bf(v.z); bv.w = f2bf(v.w);
            *(ushort4*)(lB + hr * 72 + c4) = bv;
        }
        __syncthreads();
#pragma unroll
        for (int kk = 0; kk < 64; kk += 32) {
            int kcol = kk + (lane >> 4) * 8;
            bf16x8 a[4], b[2];
#pragma unroll
            for (int m = 0; m < 4; ++m)
                a[m] = *(const bf16x8*)(lA + (wr * 64 + m * 16 + (lane & 15)) * 72 + kcol);
#pragma unroll
            for (int n = 0; n < 2; ++n)
                b[n] = *(const bf16x8*)(lB + (wc * 32 + n * 16 + (lane & 15)) * 72 + kcol);
#pragma unroll
            for (int m = 0; m < 4; ++m)
#pragma unroll
                for (int n = 0; n < 2; ++n)
                    acc[m][n] = __builtin_amdgcn_mfma_f32_16x16x32_bf16(a[m], b[n], acc[m][n], 0, 0, 0);
        }
        __syncthreads();
    }

#pragma unroll
    for (int m = 0; m < 4; ++m)
#pragma unroll
        for (int n = 0; n < 2; ++n)
#pragma unroll
            for (int r = 0; r < 4; ++r) {
                int lr = wr * 64 + m * 16 + (lane >> 4) * 4 + r;
                if (rbase + lr < cnt) {
                    int col = hbase + wc * 32 + n * 16 + (lane & 15);
                    y[(size_t)(obase + rbase + lr) * HID + col] = acc[m][n][r];
                }
            }
}

// ---------------- combine: out[t] = w0*y[r0] + w1*y[r1] ----------------
__global__ void k_combine(const float* __restrict__ y, const int* __restrict__ slotrow,
                          const float* __restrict__ topkw, float* __restrict__ out) {
    int j = blockIdx.x * blockDim.x + threadIdx.x;   // T*H/4 threads
    int t = j >> 8, c = j & 255;
    int r0 = slotrow[2 * t], r1 = slotrow[2 * t + 1];
    float w0 = topkw[2 * t], w1 = topkw[2 * t + 1];
    float4 a = ((const float4*)y)[(size_t)r0 * 256 + c];
    float4 b = ((const float4*)y)[(size_t)r1 * 256 + c];
    float4 o;
    o.x = w0 * a.x + w1 * b.x;
    o.y = w0 * a.y + w1 * b.y;
    o.z = w0 * a.z + w1 * b.z;
    o.w = w0 * a.w + w1 * b.w;
    ((float4*)out)[j] = o;
}

extern "C" void kernel_launch(void* const* d_in, const int* in_sizes, int n_in,
                              void* d_out, int out_size, void* d_ws, size_t ws_size,
                              hipStream_t stream) {
    const float* x  = (const float*)d_in[0];
    const float* gw = (const float*)d_in[1];
    const float* w1 = (const float*)d_in[2];
    const float* w3 = (const float*)d_in[3];
    const float* w2 = (const float*)d_in[4];
    float* out = (float*)d_out;

    char* ws = (char*)d_ws;
    int*   counts   = (int*)(ws + WS_COUNTS);
    int*   offsets  = (int*)(ws + WS_OFFSETS);
    int*   topki    = (int*)(ws + WS_TOPKI);
    float* topkw    = (float*)(ws + WS_TOPKW);
    int*   slotpos  = (int*)(ws + WS_SLOTPOS);
    int*   slotrow  = (int*)(ws + WS_SLOTROW);
    int*   routetok = (int*)(ws + WS_ROUTETOK);
    unsigned short* xb   = (unsigned short*)(ws + WS_XBF);
    unsigned short* actb = (unsigned short*)(ws + WS_ACT);
    float* yb = (float*)(ws + WS_Y);

    hipMemsetAsync(counts, 0, 64, stream);
    k_cvt_x<<<2048, 256, 0, stream>>>(x, xb);
    k_router<<<T_TOK, 64, 0, stream>>>(x, gw, counts, topki, topkw, slotpos);
    k_prefix<<<1, 64, 0, stream>>>(counts, offsets);
    k_fill<<<16, 256, 0, stream>>>(topki, slotpos, offsets, routetok, slotrow);
    k_gemm1<<<dim3(FF / 64, T_TOK / 128, NE), 256, 0, stream>>>(xb, w1, w3, counts, offsets, routetok, actb);
    k_gemm2<<<dim3(HID / 64, T_TOK / 128, NE), 256, 0, stream>>>(actb, w2, counts, offsets, yb);
    k_combine<<<2048, 256, 0, stream>>>(yb, slotrow, topkw, out);
}

// Round 2
// 285.508 us; speedup vs baseline: 1.4973x; 1.4973x over previous
//
#include <hip/hip_runtime.h>
#include <hip/hip_bf16.h>

// Problem constants
#define T_TOK 2048
#define HID   1024
#define FF    3584
#define NE    8
#define TOPK  2
#define GRIDY 40          // >= max tiles = 4096/128 + 7

typedef __bf16 bf16x8 __attribute__((ext_vector_type(8)));
typedef float  f32x4  __attribute__((ext_vector_type(4)));
typedef unsigned short u16x8 __attribute__((ext_vector_type(8)));

// ---- workspace layout (bytes) ----
#define WS_COUNTS   0u
#define WS_OFFSETS  64u
#define WS_TILECNT  128u
#define WS_TLE      256u          // int[64]
#define WS_TLM      512u          // int[64]
#define WS_TOPKI    1024u         // int[4096]
#define WS_TOPKW    17408u        // float[4096]
#define WS_SLOTPOS  33792u        // int[4096]
#define WS_SLOTROW  50176u        // int[4096]
#define WS_ROUTETOK 66560u        // int[4096]
#define WS_XBF      131072u                           // ushort[2048*1024] (4 MB)
#define WS_ACT      (WS_XBF + 2048u*1024u*2u)         // ushort[4096*3584] (29.4 MB)
#define WS_Y        (WS_ACT + 4096u*3584u*2u)         // float[2*4096*1024] (32 MB)
// total ~64.1 MB

static __device__ __forceinline__ unsigned short f2bf(float f) {
    unsigned int u = __builtin_bit_cast(unsigned int, f);
    u += 0x7FFFu + ((u >> 16) & 1u);   // RNE
    return (unsigned short)(u >> 16);
}
// fast round-half-up pack of 2 floats -> 2 bf16 in one u32
static __device__ __forceinline__ unsigned int pack2(float a, float b) {
    unsigned int ua = __builtin_bit_cast(unsigned int, a) + 0x8000u;
    unsigned int ub = __builtin_bit_cast(unsigned int, b) + 0x8000u;
    return (ua >> 16) | (ub & 0xFFFF0000u);
}

// ---------------- x -> bf16 ----------------
__global__ void k_cvt_x(const float* __restrict__ x, unsigned short* __restrict__ xb) {
    int i = blockIdx.x * blockDim.x + threadIdx.x;
    float4 v = ((const float4*)x)[i];
    ushort4 o;
    o.x = f2bf(v.x); o.y = f2bf(v.y); o.z = f2bf(v.z); o.w = f2bf(v.w);
    ((ushort4*)xb)[i] = o;
}

// ---------------- router ----------------
__global__ void k_router(const float* __restrict__ x, const float* __restrict__ gw,
                         int* __restrict__ counts, int* __restrict__ topki,
                         float* __restrict__ topkw, int* __restrict__ slotpos) {
    int t = blockIdx.x;
    int l = threadIdx.x;
    const float* xr = x + (size_t)t * HID;
    float acc[NE];
#pragma unroll
    for (int e = 0; e < NE; ++e) acc[e] = 0.f;
#pragma unroll
    for (int i = 0; i < HID / 64; ++i) {
        int h = l + 64 * i;
        float xv = xr[h];
#pragma unroll
        for (int e = 0; e < NE; ++e) acc[e] += xv * gw[e * HID + h];
    }
#pragma unroll
    for (int e = 0; e < NE; ++e) {
#pragma unroll
        for (int off = 32; off; off >>= 1) acc[e] += __shfl_xor(acc[e], off);
    }
    if (l == 0) {
        float best = -1e30f, second = -1e30f;
        int bi = 0, si = 0;
#pragma unroll
        for (int e = 0; e < NE; ++e) {
            float v = acc[e];
            if (v > best) { second = best; si = bi; best = v; bi = e; }
            else if (v > second) { second = v; si = e; }
        }
        float w0 = 1.f / (1.f + __expf(second - best));
        float w1 = 1.f - w0;
        topki[2 * t] = bi;  topki[2 * t + 1] = si;
        topkw[2 * t] = w0;  topkw[2 * t + 1] = w1;
        slotpos[2 * t]     = atomicAdd(&counts[bi], 1);
        slotpos[2 * t + 1] = atomicAdd(&counts[si], 1);
    }
}

// ---------------- prefix + compact tile list (BM=128) ----------------
__global__ void k_prefix(const int* __restrict__ counts, int* __restrict__ offsets,
                         int* __restrict__ tle, int* __restrict__ tlm,
                         int* __restrict__ tilecnt) {
    if (threadIdx.x == 0) {
        int o = 0;
#pragma unroll
        for (int e = 0; e < NE; ++e) { offsets[e] = o; o += counts[e]; }
        int n = 0;
        for (int e = 0; e < NE; ++e) {
            int t = (counts[e] + 127) >> 7;
            for (int i = 0; i < t; ++i) { tle[n] = e; tlm[n] = i; ++n; }
        }
        tilecnt[0] = n;
    }
}

// ---------------- fill routing arrays ----------------
__global__ void k_fill(const int* __restrict__ topki, const int* __restrict__ slotpos,
                       const int* __restrict__ offsets, int* __restrict__ routetok,
                       int* __restrict__ slotrow) {
    int j = blockIdx.x * blockDim.x + threadIdx.x;
    if (j >= T_TOK * TOPK) return;
    int e = topki[j];
    int row = offsets[e] + slotpos[j];
    routetok[row] = j >> 1;
    slotrow[j] = row;
}

// ---------------- GEMM1: act = silu(Xe@w1^T) * (Xe@w3^T) ----------------
__global__ __launch_bounds__(256) void k_gemm1(
    const unsigned short* __restrict__ xb, const float* __restrict__ w1,
    const float* __restrict__ w3, const int* __restrict__ counts,
    const int* __restrict__ offsets, const int* __restrict__ routetok,
    const int* __restrict__ tle, const int* __restrict__ tlm,
    const int* __restrict__ tilecnt, unsigned short* __restrict__ act)
{
    int by = blockIdx.y;
    if (by >= tilecnt[0]) return;
    int e = tle[by], mtile = tlm[by];
    int cnt = counts[e], obase = offsets[e];
    int rbase = mtile * 128;
    int fbase = blockIdx.x * 64;

    __shared__ __align__(16) unsigned short lA[128 * 72];
    __shared__ __align__(16) unsigned short lB1[64 * 72];
    __shared__ __align__(16) unsigned short lB3[64 * 72];
    __shared__ int ltok[128];

    int tid = threadIdx.x;
    if (tid < 128) {
        int r = rbase + tid;
        ltok[tid] = (r < cnt) ? routetok[obase + r] : 0;
    }
    __syncthreads();

    // per-thread staging addresses
    const int ra0 = tid >> 3, ca = (tid & 7) * 8;
    const int rb0 = tid >> 4, cb = (tid & 15) * 4;
    const unsigned short* pa[4];
    const float* pb1[4];
    const float* pb3[4];
    const float* w1e = w1 + ((size_t)e * FF + fbase) * HID;
    const float* w3e = w3 + ((size_t)e * FF + fbase) * HID;
#pragma unroll
    for (int i = 0; i < 4; ++i) {
        pa[i]  = xb + (size_t)ltok[ra0 + 32 * i] * HID + ca;
        pb1[i] = w1e + (size_t)(rb0 + 16 * i) * HID + cb;
        pb3[i] = w3e + (size_t)(rb0 + 16 * i) * HID + cb;
    }

    int lane = tid & 63, wv = tid >> 6, wr = wv >> 1, wc = wv & 1;
    f32x4 accg[4][2], accu[4][2];
#pragma unroll
    for (int m = 0; m < 4; ++m)
#pragma unroll
        for (int n = 0; n < 2; ++n) {
            accg[m][n] = (f32x4){0.f, 0.f, 0.f, 0.f};
            accu[m][n] = (f32x4){0.f, 0.f, 0.f, 0.f};
        }

    u16x8 ra[4]; float4 r1[4], r3[4];
#pragma unroll
    for (int i = 0; i < 4; ++i) {
        ra[i] = *(const u16x8*)(pa[i]);
        r1[i] = *(const float4*)(pb1[i]);
        r3[i] = *(const float4*)(pb3[i]);
    }

    for (int kt = 0; kt < HID / 64; ++kt) {
        // write staged regs to LDS
#pragma unroll
        for (int i = 0; i < 4; ++i) {
            *(u16x8*)(lA + (ra0 + 32 * i) * 72 + ca) = ra[i];
            uint2 p1; p1.x = pack2(r1[i].x, r1[i].y); p1.y = pack2(r1[i].z, r1[i].w);
            uint2 p3; p3.x = pack2(r3[i].x, r3[i].y); p3.y = pack2(r3[i].z, r3[i].w);
            *(uint2*)(lB1 + (rb0 + 16 * i) * 72 + cb) = p1;
            *(uint2*)(lB3 + (rb0 + 16 * i) * 72 + cb) = p3;
        }
        __syncthreads();
        // issue next K-step loads (overlap with MFMA below)
        if (kt < HID / 64 - 1) {
            int kof = (kt + 1) * 64;
#pragma unroll
            for (int i = 0; i < 4; ++i) {
                ra[i] = *(const u16x8*)(pa[i] + kof);
                r1[i] = *(const float4*)(pb1[i] + kof);
                r3[i] = *(const float4*)(pb3[i] + kof);
            }
        }
#pragma unroll
        for (int kk = 0; kk < 64; kk += 32) {
            int kcol = kk + (lane >> 4) * 8;
            bf16x8 a[4], b1[2], b3[2];
#pragma unroll
            for (int m = 0; m < 4; ++m)
                a[m] = *(const bf16x8*)(lA + (wr * 64 + m * 16 + (lane & 15)) * 72 + kcol);
#pragma unroll
            for (int n = 0; n < 2; ++n) {
                b1[n] = *(const bf16x8*)(lB1 + (wc * 32 + n * 16 + (lane & 15)) * 72 + kcol);
                b3[n] = *(const bf16x8*)(lB3 + (wc * 32 + n * 16 + (lane & 15)) * 72 + kcol);
            }
#pragma unroll
            for (int m = 0; m < 4; ++m)
#pragma unroll
                for (int n = 0; n < 2; ++n) {
                    accg[m][n] = __builtin_amdgcn_mfma_f32_16x16x32_bf16(a[m], b1[n], accg[m][n], 0, 0, 0);
                    accu[m][n] = __builtin_amdgcn_mfma_f32_16x16x32_bf16(a[m], b3[n], accu[m][n], 0, 0, 0);
                }
        }
        __syncthreads();
    }

#pragma unroll
    for (int m = 0; m < 4; ++m)
#pragma unroll
        for (int n = 0; n < 2; ++n)
#pragma unroll
            for (int r = 0; r < 4; ++r) {
                int lr = wr * 64 + m * 16 + (lane >> 4) * 4 + r;
                if (rbase + lr < cnt) {
                    float g = accg[m][n][r], u = accu[m][n][r];
                    float s = g / (1.f + __expf(-g));
                    int col = fbase + wc * 32 + n * 16 + (lane & 15);
                    act[(size_t)(obase + rbase + lr) * FF + col] = f2bf(s * u);
                }
            }
}

// ---------------- GEMM2: y[z] = act @ w2^T  (split-K = 2) ----------------
__global__ __launch_bounds__(256) void k_gemm2(
    const unsigned short* __restrict__ act, const float* __restrict__ w2,
    const int* __restrict__ counts, const int* __restrict__ offsets,
    const int* __restrict__ tle, const int* __restrict__ tlm,
    const int* __restrict__ tilecnt, float* __restrict__ y)
{
    int by = blockIdx.y;
    if (by >= tilecnt[0]) return;
    int e = tle[by], mtile = tlm[by];
    int cnt = counts[e], obase = offsets[e];
    int rbase = mtile * 128;
    int hbase = blockIdx.x * 64;
    int z = blockIdx.z;               // K half
    const int KS = FF / 64 / 2;       // 28 k-steps per half

    __shared__ __align__(16) unsigned short lA[128 * 72];
    __shared__ __align__(16) unsigned short lB[64 * 72];

    int tid = threadIdx.x;
    const int ra0 = tid >> 3, ca = (tid & 7) * 8;
    const int rb0 = tid >> 4, cb = (tid & 15) * 4;
    const unsigned short* pa[4];
    const float* pb[4];
    const float* w2e = w2 + ((size_t)e * HID + hbase) * FF;
    int kbase0 = z * KS * 64;
#pragma unroll
    for (int i = 0; i < 4; ++i) {
        int rowg = obase + rbase + ra0 + 32 * i;
        if (rowg > 4095) rowg = 4095;
        pa[i] = act + (size_t)rowg * FF + ca + kbase0;
        pb[i] = w2e + (size_t)(rb0 + 16 * i) * FF + cb + kbase0;
    }

    int lane = tid & 63, wv = tid >> 6, wr = wv >> 1, wc = wv & 1;
    f32x4 acc[4][2];
#pragma unroll
    for (int m = 0; m < 4; ++m)
#pragma unroll
        for (int n = 0; n < 2; ++n) acc[m][n] = (f32x4){0.f, 0.f, 0.f, 0.f};

    u16x8 ra[4]; float4 rb[4];
#pragma unroll
    for (int i = 0; i < 4; ++i) {
        ra[i] = *(const u16x8*)(pa[i]);
        rb[i] = *(const float4*)(pb[i]);
    }

    for (int kt = 0; kt < KS; ++kt) {
#pragma unroll
        for (int i = 0; i < 4; ++i) {
            *(u16x8*)(lA + (ra0 + 32 * i) * 72 + ca) = ra[i];
            uint2 p; p.x = pack2(rb[i].x, rb[i].y); p.y = pack2(rb[i].z, rb[i].w);
            *(uint2*)(lB + (rb0 + 16 * i) * 72 + cb) = p;
        }
        __syncthreads();
        if (kt < KS - 1) {
            int kof = (kt + 1) * 64;
#pragma unroll
            for (int i = 0; i < 4; ++i) {
                ra[i] = *(const u16x8*)(pa[i] + kof);
                rb[i] = *(const float4*)(pb[i] + kof);
            }
        }
#pragma unroll
        for (int kk = 0; kk < 64; kk += 32) {
            int kcol = kk + (lane >> 4) * 8;
            bf16x8 a[4], b[2];
#pragma unroll
            for (int m = 0; m < 4; ++m)
                a[m] = *(const bf16x8*)(lA + (wr * 64 + m * 16 + (lane & 15)) * 72 + kcol);
#pragma unroll
            for (int n = 0; n < 2; ++n)
                b[n] = *(const bf16x8*)(lB + (wc * 32 + n * 16 + (lane & 15)) * 72 + kcol);
#pragma unroll
            for (int m = 0; m < 4; ++m)
#pragma unroll
                for (int n = 0; n < 2; ++n)
                    acc[m][n] = __builtin_amdgcn_mfma_f32_16x16x32_bf16(a[m], b[n], acc[m][n], 0, 0, 0);
        }
        __syncthreads();
    }

    float* yz = y + (size_t)z * T_TOK * TOPK * HID;
#pragma unroll
    for (int m = 0; m < 4; ++m)
#pragma unroll
        for (int n = 0; n < 2; ++n)
#pragma unroll
            for (int r = 0; r < 4; ++r) {
                int lr = wr * 64 + m * 16 + (lane >> 4) * 4 + r;
                if (rbase + lr < cnt) {
                    int col = hbase + wc * 32 + n * 16 + (lane & 15);
                    yz[(size_t)(obase + rbase + lr) * HID + col] = acc[m][n][r];
                }
            }
}

// ---------------- combine ----------------
__global__ void k_combine(const float* __restrict__ y, const int* __restrict__ slotrow,
                          const float* __restrict__ topkw, float* __restrict__ out) {
    int j = blockIdx.x * blockDim.x + threadIdx.x;
    int t = j >> 8, c = j & 255;
    int r0 = slotrow[2 * t], r1 = slotrow[2 * t + 1];
    float w0 = topkw[2 * t], w1 = topkw[2 * t + 1];
    const float4* y0 = (const float4*)y;
    const float4* y1 = (const float4*)(y + (size_t)T_TOK * TOPK * HID);
    float4 a0 = y0[(size_t)r0 * 256 + c], a1 = y1[(size_t)r0 * 256 + c];
    float4 b0 = y0[(size_t)r1 * 256 + c], b1 = y1[(size_t)r1 * 256 + c];
    float4 o;
    o.x = w0 * (a0.x + a1.x) + w1 * (b0.x + b1.x);
    o.y = w0 * (a0.y + a1.y) + w1 * (b0.y + b1.y);
    o.z = w0 * (a0.z + a1.z) + w1 * (b0.z + b1.z);
    o.w = w0 * (a0.w + a1.w) + w1 * (b0.w + b1.w);
    ((float4*)out)[j] = o;
}

extern "C" void kernel_launch(void* const* d_in, const int* in_sizes, int n_in,
                              void* d_out, int out_size, void* d_ws, size_t ws_size,
                              hipStream_t stream) {
    const float* x  = (const float*)d_in[0];
    const float* gw = (const float*)d_in[1];
    const float* w1 = (const float*)d_in[2];
    const float* w3 = (const float*)d_in[3];
    const float* w2 = (const float*)d_in[4];
    float* out = (float*)d_out;

    char* ws = (char*)d_ws;
    int*   counts   = (int*)(ws + WS_COUNTS);
    int*   offsets  = (int*)(ws + WS_OFFSETS);
    int*   tilecnt  = (int*)(ws + WS_TILECNT);
    int*   tle      = (int*)(ws + WS_TLE);
    int*   tlm      = (int*)(ws + WS_TLM);
    int*   topki    = (int*)(ws + WS_TOPKI);
    float* topkw    = (float*)(ws + WS_TOPKW);
    int*   slotpos  = (int*)(ws + WS_SLOTPOS);
    int*   slotrow  = (int*)(ws + WS_SLOTROW);
    int*   routetok = (int*)(ws + WS_ROUTETOK);
    unsigned short* xb   = (unsigned short*)(ws + WS_XBF);
    unsigned short* actb = (unsigned short*)(ws + WS_ACT);
    float* yb = (float*)(ws + WS_Y);

    hipMemsetAsync(counts, 0, 64, stream);
    k_cvt_x<<<2048, 256, 0, stream>>>(x, xb);
    k_router<<<T_TOK, 64, 0, stream>>>(x, gw, counts, topki, topkw, slotpos);
    k_prefix<<<1, 64, 0, stream>>>(counts, offsets, tle, tlm, tilecnt);
    k_fill<<<16, 256, 0, stream>>>(topki, slotpos, offsets, routetok, slotrow);
    k_gemm1<<<dim3(FF / 64, GRIDY, 1), 256, 0, stream>>>(xb, w1, w3, counts, offsets, routetok, tle, tlm, tilecnt, actb);
    k_gemm2<<<dim3(HID / 64, GRIDY, 2), 256, 0, stream>>>(actb, w2, counts, offsets, tle, tlm, tilecnt, yb);
    k_combine<<<2048, 256, 0, stream>>>(yb, slotrow, topkw, out);
}